// Round 6
// baseline (313.673 us; speedup 1.0000x reference)
//
#include <hip/hip_runtime.h>

// degcnt[i] packed u32: [31:26] = count (<=63), [25:0] = sum(w) * 2^20 fixed point
#define CNT_SHIFT 26
#define DEG_MASK  ((1u << CNT_SHIFT) - 1)
#define DEG_SCALE 1048576.0f   // 2^20

__device__ __forceinline__ unsigned pack_edge(float w) {
    return (1u << CNT_SHIFT) + (unsigned)(w * DEG_SCALE + 0.5f);
}
__device__ __forceinline__ float bf16_to_f(unsigned short u) {
    return __uint_as_float(((unsigned int)u) << 16);
}
__device__ __forceinline__ unsigned short f_to_bf16(float f) {
    unsigned int u = __float_as_uint(f);
    u += 0x7fffu + ((u >> 16) & 1u);   // round-to-nearest-even
    return (unsigned short)(u >> 16);
}
// ep word: [31:15] = src (17b), [14:0] = bf16(norm) sans sign (norm >= 0)
__device__ __forceinline__ unsigned int pack_ep(int src, float nm) {
    return ((unsigned int)src << 15) | (unsigned int)(f_to_bf16(nm) & 0x7fff);
}
__device__ __forceinline__ float ep_norm(unsigned int e) {
    return __uint_as_float((e & 0x7fffu) << 16);
}

// ---- fused: [0,nDeg) blocks = degree+count+rank atomics; rest = h1 = x@W1 ----
__global__ void k_pre(const int4* __restrict__ col4, const float4* __restrict__ w4,
                      const int* __restrict__ col, const float* __restrict__ w,
                      unsigned* __restrict__ degcnt, unsigned short* __restrict__ rank,
                      const float* __restrict__ x, const float* __restrict__ W1,
                      unsigned short* __restrict__ h1b,
                      int E4, int rem_base, int rem, int nDeg, int nGemm, int n) {
    __shared__ float Ws[64 * 64];
    if ((int)blockIdx.x < nDeg) {
        int t = blockIdx.x * 256 + threadIdx.x;
        if (t < E4) {
            int4   c = col4[t];
            float4 v = w4[t];
            unsigned o0 = atomicAdd(&degcnt[c.x], pack_edge(v.x));
            unsigned o1 = atomicAdd(&degcnt[c.y], pack_edge(v.y));
            unsigned o2 = atomicAdd(&degcnt[c.z], pack_edge(v.z));
            unsigned o3 = atomicAdd(&degcnt[c.w], pack_edge(v.w));
            ushort4 r4;
            r4.x = (unsigned short)(o0 >> CNT_SHIFT);
            r4.y = (unsigned short)(o1 >> CNT_SHIFT);
            r4.z = (unsigned short)(o2 >> CNT_SHIFT);
            r4.w = (unsigned short)(o3 >> CNT_SHIFT);
            *(ushort4*)(rank + 4 * (size_t)t) = r4;
        }
        if (t < rem) {
            int e = rem_base + t;
            unsigned o = atomicAdd(&degcnt[col[e]], pack_edge(w[e]));
            rank[e] = (unsigned short)(o >> CNT_SHIFT);
        }
    } else {
        int b = blockIdx.x - nDeg;
        for (int t = threadIdx.x; t < 4096; t += 256) Ws[t] = W1[t];
        __syncthreads();
        int lane = threadIdx.x & 63;
        int wave = threadIdx.x >> 6;
        for (int i = b * 4 + wave; i < n; i += nGemm * 4) {
            float xv = x[(size_t)i * 64 + lane];
            float acc = 0.f;
#pragma unroll
            for (int k = 0; k < 64; ++k) {
                float xk = __shfl(xv, k, 64);
                acc = fmaf(xk, Ws[k * 64 + lane], acc);
            }
            h1b[(size_t)i * 64 + lane] = f_to_bf16(acc);
        }
    }
}

// ---- scan1 + scan2 fused (last-block pattern). Emits dinv, local-excl, scanned parts ----
__global__ __launch_bounds__(1024) void k_scan12(const unsigned* __restrict__ degcnt,
                                                 float* __restrict__ dinv,
                                                 int* __restrict__ excl, int* __restrict__ parts,
                                                 unsigned* __restrict__ done, int n, int nb) {
    __shared__ int sm[1024];
    __shared__ int lastflag;
    int gid = blockIdx.x * 1024 + threadIdx.x;
    int v = 0;
    if (gid < n) {
        unsigned dc = degcnt[gid];
        v = (int)(dc >> CNT_SHIFT);
        dinv[gid] = rsqrtf((float)(dc & DEG_MASK) * (1.0f / DEG_SCALE) + 1.0f);
    }
    sm[threadIdx.x] = v;
    __syncthreads();
    for (int off = 1; off < 1024; off <<= 1) {
        int t = (threadIdx.x >= off) ? sm[threadIdx.x - off] : 0;
        __syncthreads();
        sm[threadIdx.x] += t;
        __syncthreads();
    }
    if (gid < n) excl[gid] = sm[threadIdx.x] - v;
    if (threadIdx.x == 1023) parts[blockIdx.x] = sm[1023];
    __syncthreads();
    if (threadIdx.x == 0) {
        __threadfence();
        lastflag = (atomicAdd(done, 1u) == (unsigned)(nb - 1));
    }
    __syncthreads();
    if (lastflag) {                      // this block arrives last: scan parts in-place
        __threadfence();
        int pv = (threadIdx.x < nb) ? parts[threadIdx.x] : 0;
        sm[threadIdx.x] = pv;
        __syncthreads();
        for (int off = 1; off < 128; off <<= 1) {   // nb <= 128
            int t = (threadIdx.x >= off && threadIdx.x < 128) ? sm[threadIdx.x - off] : 0;
            __syncthreads();
            if (threadIdx.x < 128) sm[threadIdx.x] += t;
            __syncthreads();
        }
        if (threadIdx.x < nb) parts[threadIdx.x] = sm[threadIdx.x] - pv;
    }
}

// -------- CSR fill, atomic-free: slot = excl[col]+parts[col>>10]+rank; 4B store --------
__global__ void k_fill(const int4* __restrict__ row4, const int4* __restrict__ col4,
                       const float4* __restrict__ w4,
                       const int* __restrict__ row, const int* __restrict__ col,
                       const float* __restrict__ w,
                       const unsigned short* __restrict__ rank,
                       const int* __restrict__ excl, const int* __restrict__ parts,
                       const float* __restrict__ dinv,
                       unsigned int* __restrict__ ep,
                       int E4, int rem_base, int rem) {
    int t = blockIdx.x * 256 + threadIdx.x;
    if (t < E4) {
        int4   r = row4[t];
        int4   c = col4[t];
        float4 v = w4[t];
        ushort4 k4 = *(const ushort4*)(rank + 4 * (size_t)t);
        int s0 = excl[c.x] + parts[c.x >> 10] + k4.x;
        int s1 = excl[c.y] + parts[c.y >> 10] + k4.y;
        int s2 = excl[c.z] + parts[c.z >> 10] + k4.z;
        int s3 = excl[c.w] + parts[c.w >> 10] + k4.w;
        ep[s0] = pack_ep(r.x, dinv[r.x] * v.x * dinv[c.x]);
        ep[s1] = pack_ep(r.y, dinv[r.y] * v.y * dinv[c.y]);
        ep[s2] = pack_ep(r.z, dinv[r.z] * v.z * dinv[c.z]);
        ep[s3] = pack_ep(r.w, dinv[r.w] * v.w * dinv[c.w]);
    }
    if (t < rem) {
        int e = rem_base + t;
        int r = row[e], c = col[e];
        ep[excl[c] + parts[c >> 10] + rank[e]] = pack_ep(r, dinv[r] * w[e] * dinv[c]);
    }
}

// ---- agg1 fused: bf16 gather-sum (4-way unrolled) + b1 + relu + dot(W2) -> h2[N] ----
__global__ void k_agg1(const unsigned short* __restrict__ h1b,
                       const int* __restrict__ excl, const int* __restrict__ parts,
                       const unsigned int* __restrict__ ep, const float* __restrict__ dinv,
                       const float* __restrict__ b1, const float* __restrict__ W2,
                       float* __restrict__ h2, int n, int Etot) {
    int lane = threadIdx.x & 63;
    int wave = threadIdx.x >> 6;
    int i = blockIdx.x * 4 + wave;
    if (i >= n) return;
    float di = dinv[i];
    float acc = bf16_to_f(h1b[(size_t)i * 64 + lane]) * (di * di);   // self-loop
    int s0 = excl[i] + parts[i >> 10];
    int s1 = (i + 1 < n) ? excl[i + 1] + parts[(i + 1) >> 10] : Etot;
    int s = s0;
    for (; s + 4 <= s1; s += 4) {
        unsigned int e0 = ep[s], e1 = ep[s + 1], e2 = ep[s + 2], e3 = ep[s + 3];
        float v0 = bf16_to_f(h1b[(size_t)(e0 >> 15) * 64 + lane]);
        float v1 = bf16_to_f(h1b[(size_t)(e1 >> 15) * 64 + lane]);
        float v2 = bf16_to_f(h1b[(size_t)(e2 >> 15) * 64 + lane]);
        float v3 = bf16_to_f(h1b[(size_t)(e3 >> 15) * 64 + lane]);
        acc = fmaf(v0, ep_norm(e0), acc);
        acc = fmaf(v1, ep_norm(e1), acc);
        acc = fmaf(v2, ep_norm(e2), acc);
        acc = fmaf(v3, ep_norm(e3), acc);
    }
    for (; s < s1; ++s) {
        unsigned int e = ep[s];
        acc = fmaf(bf16_to_f(h1b[(size_t)(e >> 15) * 64 + lane]), ep_norm(e), acc);
    }
    float v = fmaxf(acc + b1[lane], 0.f);
    float p = v * W2[lane];
#pragma unroll
    for (int o = 32; o > 0; o >>= 1) p += __shfl_down(p, o, 64);
    if (lane == 0) h2[i] = p;
}

// ---------------- agg2 on scalars (4-way unrolled) + b2 -> out[N] ----------------
__global__ void k_agg2(const float* __restrict__ h2,
                       const int* __restrict__ excl, const int* __restrict__ parts,
                       const unsigned int* __restrict__ ep, const float* __restrict__ dinv,
                       const float* __restrict__ b2, float* __restrict__ out, int n, int Etot) {
    int i = blockIdx.x * 256 + threadIdx.x;
    if (i >= n) return;
    float di = dinv[i];
    float acc = h2[i] * di * di;       // self-loop
    int s0 = excl[i] + parts[i >> 10];
    int s1 = (i + 1 < n) ? excl[i + 1] + parts[(i + 1) >> 10] : Etot;
    int s = s0;
    for (; s + 4 <= s1; s += 4) {
        unsigned int e0 = ep[s], e1 = ep[s + 1], e2 = ep[s + 2], e3 = ep[s + 3];
        float v0 = h2[e0 >> 15];
        float v1 = h2[e1 >> 15];
        float v2 = h2[e2 >> 15];
        float v3 = h2[e3 >> 15];
        acc = fmaf(v0, ep_norm(e0), acc);
        acc = fmaf(v1, ep_norm(e1), acc);
        acc = fmaf(v2, ep_norm(e2), acc);
        acc = fmaf(v3, ep_norm(e3), acc);
    }
    for (; s < s1; ++s) {
        unsigned int e = ep[s];
        acc = fmaf(h2[e >> 15], ep_norm(e), acc);
    }
    out[i] = acc + b2[0];
}

extern "C" void kernel_launch(void* const* d_in, const int* in_sizes, int n_in,
                              void* d_out, int out_size, void* d_ws, size_t ws_size,
                              hipStream_t stream) {
    const float* x  = (const float*)d_in[0];
    const int*   ei = (const int*)d_in[1];
    const float* w  = (const float*)d_in[2];
    const float* W1 = (const float*)d_in[3];
    const float* b1 = (const float*)d_in[4];
    const float* W2 = (const float*)d_in[5];
    const float* b2 = (const float*)d_in[6];
    float* out = (float*)d_out;

    const int N = in_sizes[0] / 64;
    const int E = in_sizes[2];
    const int* row = ei;
    const int* col = ei + E;

    // workspace carve-up (~22 MB); 8B-aligned chunks first
    char* p = (char*)d_ws;
    unsigned* degcnt = (unsigned*)p; p += (size_t)N * 4;   // + done counter right after
    unsigned* done   = (unsigned*)p; p += 8;               // zeroed together with degcnt
    unsigned short* rank = (unsigned short*)p; p += (size_t)E * 2;
    unsigned short* h1b  = (unsigned short*)p; p += (size_t)N * 64 * 2;
    float*  dinv = (float*)p;   p += (size_t)N * 4;
    int*    excl = (int*)p;     p += (size_t)N * 4;
    int*    parts= (int*)p;     p += 1024;
    unsigned int* ep = (unsigned int*)p; p += (size_t)E * 4;
    float*  h2   = (float*)p;   p += (size_t)N * 4;

    const int E4       = E / 4;
    const int rem_base = E4 * 4;
    const int rem      = E - rem_base;
    const int nDeg  = (max(E4, rem) + 255) / 256;
    const int nGemm = 1024;
    const int gN  = (N + 255) / 256;
    const int nb1 = (N + 1023) / 1024;   // 98 <= 128

    (void)hipMemsetAsync(degcnt, 0, (size_t)N * 4 + 8, stream);
    k_pre<<<nDeg + nGemm, 256, 0, stream>>>((const int4*)col, (const float4*)w, col, w,
                                            degcnt, rank, x, W1, h1b,
                                            E4, rem_base, rem, nDeg, nGemm, N);
    k_scan12<<<nb1, 1024, 0, stream>>>(degcnt, dinv, excl, parts, done, N, nb1);
    k_fill<<<nDeg, 256, 0, stream>>>((const int4*)row, (const int4*)col, (const float4*)w,
                                     row, col, w, rank, excl, parts, dinv, ep,
                                     E4, rem_base, rem);
    k_agg1<<<(N + 3) / 4, 256, 0, stream>>>(h1b, excl, parts, ep, dinv, b1, W2, h2, N, E);
    k_agg2<<<gN, 256, 0, stream>>>(h2, excl, parts, ep, dinv, b2, out, N, E);
}

// Round 7
// 273.929 us; speedup vs baseline: 1.1451x; 1.1451x over previous
//
#include <hip/hip_runtime.h>
#include <hip/hip_fp16.h>

// ---- helpers ----
__device__ __forceinline__ float bf16_to_f(unsigned short u) {
    return __uint_as_float(((unsigned int)u) << 16);
}
__device__ __forceinline__ unsigned short f_to_bf16(float f) {
    unsigned int u = __float_as_uint(f);
    u += 0x7fffu + ((u >> 16) & 1u);
    return (unsigned short)(u >> 16);
}
__device__ __forceinline__ unsigned short f_to_h16(float f) {
    __half h = __float2half(f);
    return __half_as_ushort(h);
}
__device__ __forceinline__ float h16_to_f(unsigned short u) {
    return __half2float(__ushort_as_half(u));
}
// binrec u64: [16:0]=src row, [25:17]=col&511, [41:26]=f16(w)
// ep u32:     [31:15]=src row, [14:0]=f16(w) sans sign (w>=0)

// ---- 1. fused: [0,nBlkE) = per-block bucket histogram of col; rest = h1 = x@W1 ----
__global__ __launch_bounds__(256) void k_hist_gemm(
        const int4* __restrict__ col4, const int* __restrict__ col,
        int* __restrict__ colbase, unsigned* __restrict__ done,
        const float* __restrict__ x, const float* __restrict__ W1,
        unsigned short* __restrict__ h1b,
        int E4, int rem, int nBlkE, int nGemm, int n, int nbkt) {
    __shared__ float Ws[64 * 64];
    __shared__ int h[256];
    int blk = blockIdx.x, t = threadIdx.x;
    if (blk < nBlkE) {
        if (t < nbkt) h[t] = 0;
        if (blk == 0 && t == 0) *done = 0u;
        __syncthreads();
        int g = blk * 256 + t;
        if (g < E4) {
            int4 c = col4[g];
            atomicAdd(&h[c.x >> 9], 1);
            atomicAdd(&h[c.y >> 9], 1);
            atomicAdd(&h[c.z >> 9], 1);
            atomicAdd(&h[c.w >> 9], 1);
        }
        if (blk == 0 && t < rem) atomicAdd(&h[col[4 * E4 + t] >> 9], 1);
        __syncthreads();
        if (t < nbkt) colbase[(size_t)t * nBlkE + blk] = h[t];   // transposed [bkt][blk]
    } else {
        int b = blk - nBlkE;
        for (int k = t; k < 4096; k += 256) Ws[k] = W1[k];
        __syncthreads();
        int lane = t & 63, wave = t >> 6;
        for (int i = b * 4 + wave; i < n; i += nGemm * 4) {
            float xv = x[(size_t)i * 64 + lane];
            float acc = 0.f;
#pragma unroll
            for (int k = 0; k < 64; ++k) {
                float xk = __shfl(xv, k, 64);
                acc = fmaf(xk, Ws[k * 64 + lane], acc);
            }
            h1b[(size_t)i * 64 + lane] = f_to_bf16(acc);
        }
    }
}

// ---- 2. per-bucket scan over blocks (fused bucket-base scan via last-block) ----
__global__ __launch_bounds__(256) void k_colscan(int* __restrict__ colbase,
                                                 int* __restrict__ tot, int* __restrict__ bktbase,
                                                 unsigned* __restrict__ done,
                                                 int nBlkE, int nbkt) {
    __shared__ int ssum[256];
    __shared__ int lastflag;
    int b = blockIdx.x, t = threadIdx.x;
    const int chunk = (nBlkE + 255) >> 8;   // <=8 for nBlkE<=2048
    int vals[8];
    int s = 0;
    size_t base = (size_t)b * nBlkE;
#pragma unroll
    for (int k = 0; k < 8; ++k) {
        if (k >= chunk) break;
        int idx = t * chunk + k;
        int v = (idx < nBlkE) ? colbase[base + idx] : 0;
        vals[k] = s; s += v;
    }
    ssum[t] = s;
    __syncthreads();
    for (int o = 1; o < 256; o <<= 1) {
        int v = (t >= o) ? ssum[t - o] : 0;
        __syncthreads();
        ssum[t] += v;
        __syncthreads();
    }
    int texcl = ssum[t] - s;
#pragma unroll
    for (int k = 0; k < 8; ++k) {
        if (k >= chunk) break;
        int idx = t * chunk + k;
        if (idx < nBlkE) colbase[base + idx] = vals[k] + texcl;
    }
    if (t == 255) tot[b] = ssum[255];
    __syncthreads();
    if (t == 0) {
        __threadfence();
        lastflag = (atomicAdd(done, 1u) == (unsigned)(gridDim.x - 1));
    }
    __syncthreads();
    if (lastflag) {
        __threadfence();
        int v = (t < nbkt) ? tot[t] : 0;
        ssum[t] = v;
        __syncthreads();
        for (int o = 1; o < 256; o <<= 1) {
            int u = (t >= o) ? ssum[t - o] : 0;
            __syncthreads();
            ssum[t] += u;
            __syncthreads();
        }
        if (t < nbkt) bktbase[t] = ssum[t] - v;
    }
}

// ---- 3. bin edges by bucket (LDS cursors, plain semi-local writes) ----
__global__ __launch_bounds__(256) void k_scatter(
        const int4* __restrict__ row4, const int4* __restrict__ col4, const float4* __restrict__ w4,
        const int* __restrict__ row, const int* __restrict__ col, const float* __restrict__ w,
        const int* __restrict__ colbase, const int* __restrict__ bktbase,
        unsigned long long* __restrict__ binrec,
        int E4, int rem, int nBlkE, int nbkt) {
    __shared__ int cur[256];
    int blk = blockIdx.x, t = threadIdx.x;
    if (t < nbkt) cur[t] = bktbase[t] + colbase[(size_t)t * nBlkE + blk];
    __syncthreads();
    int g = blk * 256 + t;
    if (g < E4) {
        int4   r = row4[g];
        int4   c = col4[g];
        float4 v = w4[g];
        {
            int pos = atomicAdd(&cur[c.x >> 9], 1);
            binrec[pos] = (unsigned long long)r.x | ((unsigned long long)(c.x & 511) << 17)
                        | ((unsigned long long)f_to_h16(v.x) << 26);
        }
        {
            int pos = atomicAdd(&cur[c.y >> 9], 1);
            binrec[pos] = (unsigned long long)r.y | ((unsigned long long)(c.y & 511) << 17)
                        | ((unsigned long long)f_to_h16(v.y) << 26);
        }
        {
            int pos = atomicAdd(&cur[c.z >> 9], 1);
            binrec[pos] = (unsigned long long)r.z | ((unsigned long long)(c.z & 511) << 17)
                        | ((unsigned long long)f_to_h16(v.z) << 26);
        }
        {
            int pos = atomicAdd(&cur[c.w >> 9], 1);
            binrec[pos] = (unsigned long long)r.w | ((unsigned long long)(c.w & 511) << 17)
                        | ((unsigned long long)f_to_h16(v.w) << 26);
        }
    }
    if (blk == 0 && t < rem) {
        int e = 4 * E4 + t;
        int c = col[e];
        int pos = atomicAdd(&cur[c >> 9], 1);
        binrec[pos] = (unsigned long long)row[e] | ((unsigned long long)(c & 511) << 17)
                    | ((unsigned long long)f_to_h16(w[e]) << 26);
    }
}

// ---- 4. per-bucket: degree/wsum -> dinv + off; rank -> ep (all LDS atomics) ----
__global__ __launch_bounds__(256) void k_bucket(
        const unsigned long long* __restrict__ binrec, const int* __restrict__ bktbase,
        float* __restrict__ dinv, int* __restrict__ off, unsigned* __restrict__ ep,
        int E, int N, int nbkt) {
    __shared__ int   cnt[512];
    __shared__ float wsum[512];
    __shared__ int   loff[512];
    __shared__ int   ssum[256];
    int b = blockIdx.x, t = threadIdx.x;
    int e0 = bktbase[b];
    int e1 = (b == nbkt - 1) ? E : bktbase[b + 1];
    cnt[t] = 0; cnt[t + 256] = 0;
    wsum[t] = 0.f; wsum[t + 256] = 0.f;
    __syncthreads();
    for (int i = e0 + t; i < e1; i += 256) {
        unsigned long long rec = binrec[i];
        int cl = (int)((rec >> 17) & 511);
        atomicAdd(&cnt[cl], 1);
        atomicAdd(&wsum[cl], h16_to_f((unsigned short)(rec >> 26)));
    }
    __syncthreads();
    int c0 = cnt[2 * t], c1 = cnt[2 * t + 1];
    int ps = c0 + c1;
    ssum[t] = ps;
    __syncthreads();
    for (int o = 1; o < 256; o <<= 1) {
        int v = (t >= o) ? ssum[t - o] : 0;
        __syncthreads();
        ssum[t] += v;
        __syncthreads();
    }
    int excl = ssum[t] - ps;
    loff[2 * t] = excl;
    loff[2 * t + 1] = excl + c0;
    int id0 = (b << 9) + 2 * t, id1 = id0 + 1;
    if (id0 < N) dinv[id0] = rsqrtf(wsum[2 * t] + 1.0f);
    if (id1 < N) dinv[id1] = rsqrtf(wsum[2 * t + 1] + 1.0f);
    if (id0 <= N) off[id0] = e0 + loff[2 * t];
    if (id1 <= N) off[id1] = e0 + loff[2 * t + 1];
    __syncthreads();
    cnt[t] = 0; cnt[t + 256] = 0;
    __syncthreads();
    for (int i = e0 + t; i < e1; i += 256) {
        unsigned long long rec = binrec[i];
        int cl  = (int)((rec >> 17) & 511);
        int src = (int)(rec & 0x1FFFF);
        unsigned hb = (unsigned)((rec >> 26) & 0xFFFF);
        int pos = atomicAdd(&cnt[cl], 1);
        ep[e0 + loff[cl] + pos] = ((unsigned)src << 15) | (hb & 0x7fffu);
    }
}

// ---- 5. agg1: acc = sum w*dinv[s]*h1[s] (+self); h2 = dinv*( relu(dinv*acc+b1)@W2 ) ----
__global__ void k_agg1(const unsigned short* __restrict__ h1b, const int* __restrict__ off,
                       const unsigned* __restrict__ ep, const float* __restrict__ dinv,
                       const float* __restrict__ b1, const float* __restrict__ W2,
                       float* __restrict__ h2, int n) {
    int lane = threadIdx.x & 63;
    int wave = threadIdx.x >> 6;
    int i = blockIdx.x * 4 + wave;
    if (i >= n) return;
    float di = dinv[i];
    float acc = di * bf16_to_f(h1b[(size_t)i * 64 + lane]);   // self-loop (w=1)
    int s0 = off[i], s1 = off[i + 1];
    int s = s0;
    for (; s + 4 <= s1; s += 4) {
        unsigned e0 = ep[s], e1 = ep[s + 1], e2 = ep[s + 2], e3 = ep[s + 3];
        float d0 = dinv[e0 >> 15], d1 = dinv[e1 >> 15], d2 = dinv[e2 >> 15], d3 = dinv[e3 >> 15];
        float v0 = bf16_to_f(h1b[(size_t)(e0 >> 15) * 64 + lane]);
        float v1 = bf16_to_f(h1b[(size_t)(e1 >> 15) * 64 + lane]);
        float v2 = bf16_to_f(h1b[(size_t)(e2 >> 15) * 64 + lane]);
        float v3 = bf16_to_f(h1b[(size_t)(e3 >> 15) * 64 + lane]);
        acc = fmaf(v0, d0 * h16_to_f((unsigned short)(e0 & 0x7fff)), acc);
        acc = fmaf(v1, d1 * h16_to_f((unsigned short)(e1 & 0x7fff)), acc);
        acc = fmaf(v2, d2 * h16_to_f((unsigned short)(e2 & 0x7fff)), acc);
        acc = fmaf(v3, d3 * h16_to_f((unsigned short)(e3 & 0x7fff)), acc);
    }
    for (; s < s1; ++s) {
        unsigned e = ep[s];
        float d = dinv[e >> 15];
        acc = fmaf(bf16_to_f(h1b[(size_t)(e >> 15) * 64 + lane]),
                   d * h16_to_f((unsigned short)(e & 0x7fff)), acc);
    }
    float v = fmaxf(di * acc + b1[lane], 0.f);
    float p = v * W2[lane];
#pragma unroll
    for (int o = 32; o > 0; o >>= 1) p += __shfl_down(p, o, 64);
    if (lane == 0) h2[i] = di * p;      // store t' = dinv * t
}

// ---- 6. agg2 on pre-scaled scalars: out = dinv*( sum w*t'[s] + t'[i] ) + b2 ----
__global__ void k_agg2(const float* __restrict__ h2, const int* __restrict__ off,
                       const unsigned* __restrict__ ep, const float* __restrict__ dinv,
                       const float* __restrict__ b2, float* __restrict__ out, int n) {
    int i = blockIdx.x * 256 + threadIdx.x;
    if (i >= n) return;
    float acc = h2[i];                  // self term: t'_i = dinv_i * t_i
    int s0 = off[i], s1 = off[i + 1];
    int s = s0;
    for (; s + 4 <= s1; s += 4) {
        unsigned e0 = ep[s], e1 = ep[s + 1], e2 = ep[s + 2], e3 = ep[s + 3];
        float v0 = h2[e0 >> 15];
        float v1 = h2[e1 >> 15];
        float v2 = h2[e2 >> 15];
        float v3 = h2[e3 >> 15];
        acc = fmaf(v0, h16_to_f((unsigned short)(e0 & 0x7fff)), acc);
        acc = fmaf(v1, h16_to_f((unsigned short)(e1 & 0x7fff)), acc);
        acc = fmaf(v2, h16_to_f((unsigned short)(e2 & 0x7fff)), acc);
        acc = fmaf(v3, h16_to_f((unsigned short)(e3 & 0x7fff)), acc);
    }
    for (; s < s1; ++s) {
        unsigned e = ep[s];
        acc = fmaf(h2[e >> 15], h16_to_f((unsigned short)(e & 0x7fff)), acc);
    }
    out[i] = dinv[i] * acc + b2[0];
}

extern "C" void kernel_launch(void* const* d_in, const int* in_sizes, int n_in,
                              void* d_out, int out_size, void* d_ws, size_t ws_size,
                              hipStream_t stream) {
    const float* x  = (const float*)d_in[0];
    const int*   ei = (const int*)d_in[1];
    const float* w  = (const float*)d_in[2];
    const float* W1 = (const float*)d_in[3];
    const float* b1 = (const float*)d_in[4];
    const float* W2 = (const float*)d_in[5];
    const float* b2 = (const float*)d_in[6];
    float* out = (float*)d_out;

    const int N = in_sizes[0] / 64;
    const int E = in_sizes[2];
    const int* row = ei;
    const int* col = ei + E;

    const int nbkt  = (N + 511) >> 9;          // 196 buckets of 512 nodes
    const int E4    = E / 4;
    const int rem   = E - 4 * E4;
    const int nBlkE = (E4 + 255) / 256;        // 1250
    const int nGemm = 1024;

    // workspace carve-up (~30 MB); 8B-aligned chunks first
    char* p = (char*)d_ws;
    unsigned long long* binrec = (unsigned long long*)p; p += (size_t)E * 8;
    int* colbase = (int*)p; p += (size_t)nbkt * nBlkE * 4;
    int* tot     = (int*)p; p += (size_t)nbkt * 4;
    int* bktbase = (int*)p; p += (size_t)(nbkt + 1) * 4;
    unsigned* done = (unsigned*)p; p += 16;
    unsigned short* h1b = (unsigned short*)p; p += (size_t)N * 64 * 2;
    float* dinv = (float*)p; p += (size_t)N * 4;
    int*   off  = (int*)p;   p += (size_t)(N + 1) * 4;
    unsigned* ep = (unsigned*)p; p += (size_t)E * 4;
    float* h2   = (float*)p; p += (size_t)N * 4;

    k_hist_gemm<<<nBlkE + nGemm, 256, 0, stream>>>((const int4*)col, col, colbase, done,
                                                   x, W1, h1b, E4, rem, nBlkE, nGemm, N, nbkt);
    k_colscan<<<nbkt, 256, 0, stream>>>(colbase, tot, bktbase, done, nBlkE, nbkt);
    k_scatter<<<nBlkE, 256, 0, stream>>>((const int4*)row, (const int4*)col, (const float4*)w,
                                         row, col, w, colbase, bktbase, binrec,
                                         E4, rem, nBlkE, nbkt);
    k_bucket<<<nbkt, 256, 0, stream>>>(binrec, bktbase, dinv, off, ep, E, N, nbkt);
    k_agg1<<<(N + 3) / 4, 256, 0, stream>>>(h1b, off, ep, dinv, b1, W2, h2, N);
    k_agg2<<<(N + 255) / 256, 256, 0, stream>>>(h2, off, ep, dinv, b2, out, N);
}

// Round 8
// 226.294 us; speedup vs baseline: 1.3861x; 1.2105x over previous
//
#include <hip/hip_runtime.h>
#include <hip/hip_fp16.h>

#define CNT_SHIFT 26
#define DEG_MASK  ((1u << CNT_SHIFT) - 1)
#define DEG_SCALE 1048576.0f   // 2^20

// ---- helpers ----
__device__ __forceinline__ float bf16_to_f(unsigned short u) {
    return __uint_as_float(((unsigned int)u) << 16);
}
__device__ __forceinline__ unsigned short f_to_bf16(float f) {
    unsigned int u = __float_as_uint(f);
    u += 0x7fffu + ((u >> 16) & 1u);
    return (unsigned short)(u >> 16);
}
__device__ __forceinline__ unsigned short f_to_h16(float f) {
    return __half_as_ushort(__float2half(f));
}
__device__ __forceinline__ float h16_to_f(unsigned short u) {
    return __half2float(__ushort_as_half(u));
}
// binrec u64: [16:0]=src row, [25:17]=col&511, [41:26]=f16(w)
// ep u32:     [31:15]=src row, [14:0]=f16(w) sans sign (w>=0)

// ---- 1. fused: [0,nBlkE) = per-block bucket histogram of col; rest = h1 = x@W1 ----
__global__ __launch_bounds__(256) void k_hist_gemm(
        const int4* __restrict__ col4, const int* __restrict__ col,
        int* __restrict__ colbase, unsigned* __restrict__ done,
        const float* __restrict__ x, const float* __restrict__ W1,
        unsigned short* __restrict__ h1b,
        int E4, int rem, int nBlkE, int nGemm, int n, int nbkt) {
    __shared__ int h[256];
    __shared__ float xs[4][512];     // per-wave 8-node staging
    int blk = blockIdx.x, t = threadIdx.x;
    if (blk < nBlkE) {
        if (t < nbkt) h[t] = 0;
        if (blk == 0 && t == 0) *done = 0u;
        __syncthreads();
        int g = blk * 256 + t;
        if (g < E4) {
            int4 c = col4[g];
            atomicAdd(&h[c.x >> 9], 1);
            atomicAdd(&h[c.y >> 9], 1);
            atomicAdd(&h[c.z >> 9], 1);
            atomicAdd(&h[c.w >> 9], 1);
        }
        if (blk == 0 && t < rem) atomicAdd(&h[col[4 * E4 + t] >> 9], 1);
        __syncthreads();
        if (t < nbkt) colbase[(size_t)t * nBlkE + blk] = h[t];   // transposed [bkt][blk]
    } else {
        int b = blk - nBlkE;
        int lane = t & 63, wave = t >> 6;
        float wr[64];                 // W1 column `lane`, all 64 k — registers
#pragma unroll
        for (int k = 0; k < 64; ++k) wr[k] = W1[k * 64 + lane];
        const int stride = nGemm * 32;
        for (int base = b * 32 + wave * 8; base < n; base += stride) {
            // stage 8 rows (512 floats) for this wave
            if (base + 8 <= n) {
                const float4* xsrc = (const float4*)(x + (size_t)base * 64);
                *(float4*)&xs[wave][4 * lane]       = xsrc[lane];
                *(float4*)&xs[wave][256 + 4 * lane] = xsrc[lane + 64];
            } else {
                const float* xf = x + (size_t)base * 64;
                int valid = (n - base) * 64;
                float4 a0, a1;
                int f0 = 4 * lane, f1 = 256 + 4 * lane;
                a0.x = (f0 + 0 < valid) ? xf[f0 + 0] : 0.f;
                a0.y = (f0 + 1 < valid) ? xf[f0 + 1] : 0.f;
                a0.z = (f0 + 2 < valid) ? xf[f0 + 2] : 0.f;
                a0.w = (f0 + 3 < valid) ? xf[f0 + 3] : 0.f;
                a1.x = (f1 + 0 < valid) ? xf[f1 + 0] : 0.f;
                a1.y = (f1 + 1 < valid) ? xf[f1 + 1] : 0.f;
                a1.z = (f1 + 2 < valid) ? xf[f1 + 2] : 0.f;
                a1.w = (f1 + 3 < valid) ? xf[f1 + 3] : 0.f;
                *(float4*)&xs[wave][4 * lane]       = a0;
                *(float4*)&xs[wave][256 + 4 * lane] = a1;
            }
#pragma unroll
            for (int nn = 0; nn < 8; ++nn) {
                int i = base + nn;
                if (i >= n) break;
                float acc = 0.f;
#pragma unroll
                for (int k4 = 0; k4 < 16; ++k4) {
                    float4 xv = *(const float4*)&xs[wave][nn * 64 + 4 * k4];  // broadcast
                    acc = fmaf(xv.x, wr[4 * k4 + 0], acc);
                    acc = fmaf(xv.y, wr[4 * k4 + 1], acc);
                    acc = fmaf(xv.z, wr[4 * k4 + 2], acc);
                    acc = fmaf(xv.w, wr[4 * k4 + 3], acc);
                }
                h1b[(size_t)i * 64 + lane] = f_to_bf16(acc);
            }
        }
    }
}

// ---- 2. per-bucket scan over blocks (fused bucket-base scan via last-block) ----
__global__ __launch_bounds__(256) void k_colscan(int* __restrict__ colbase,
                                                 int* __restrict__ tot, int* __restrict__ bktbase,
                                                 unsigned* __restrict__ done,
                                                 int nBlkE, int nbkt) {
    __shared__ int ssum[256];
    __shared__ int lastflag;
    int b = blockIdx.x, t = threadIdx.x;
    const int chunk = (nBlkE + 255) >> 8;
    int vals[8];
    int s = 0;
    size_t base = (size_t)b * nBlkE;
#pragma unroll
    for (int k = 0; k < 8; ++k) {
        if (k >= chunk) break;
        int idx = t * chunk + k;
        int v = (idx < nBlkE) ? colbase[base + idx] : 0;
        vals[k] = s; s += v;
    }
    ssum[t] = s;
    __syncthreads();
    for (int o = 1; o < 256; o <<= 1) {
        int v = (t >= o) ? ssum[t - o] : 0;
        __syncthreads();
        ssum[t] += v;
        __syncthreads();
    }
    int texcl = ssum[t] - s;
#pragma unroll
    for (int k = 0; k < 8; ++k) {
        if (k >= chunk) break;
        int idx = t * chunk + k;
        if (idx < nBlkE) colbase[base + idx] = vals[k] + texcl;
    }
    if (t == 255) tot[b] = ssum[255];
    __syncthreads();
    if (t == 0) {
        __threadfence();
        lastflag = (atomicAdd(done, 1u) == (unsigned)(gridDim.x - 1));
    }
    __syncthreads();
    if (lastflag) {
        __threadfence();
        int v = (t < nbkt) ? tot[t] : 0;
        ssum[t] = v;
        __syncthreads();
        for (int o = 1; o < 256; o <<= 1) {
            int u = (t >= o) ? ssum[t - o] : 0;
            __syncthreads();
            ssum[t] += u;
            __syncthreads();
        }
        if (t < nbkt) bktbase[t] = ssum[t] - v;
    }
}

// ---- 3. bin edges by bucket (LDS cursors, plain semi-local writes) ----
__global__ __launch_bounds__(256) void k_scatter(
        const int4* __restrict__ row4, const int4* __restrict__ col4, const float4* __restrict__ w4,
        const int* __restrict__ row, const int* __restrict__ col, const float* __restrict__ w,
        const int* __restrict__ colbase, const int* __restrict__ bktbase,
        unsigned long long* __restrict__ binrec,
        int E4, int rem, int nBlkE, int nbkt) {
    __shared__ int cur[256];
    int blk = blockIdx.x, t = threadIdx.x;
    if (t < nbkt) cur[t] = bktbase[t] + colbase[(size_t)t * nBlkE + blk];
    __syncthreads();
    int g = blk * 256 + t;
    if (g < E4) {
        int4   r = row4[g];
        int4   c = col4[g];
        float4 v = w4[g];
        {
            int pos = atomicAdd(&cur[c.x >> 9], 1);
            binrec[pos] = (unsigned long long)r.x | ((unsigned long long)(c.x & 511) << 17)
                        | ((unsigned long long)f_to_h16(v.x) << 26);
        }
        {
            int pos = atomicAdd(&cur[c.y >> 9], 1);
            binrec[pos] = (unsigned long long)r.y | ((unsigned long long)(c.y & 511) << 17)
                        | ((unsigned long long)f_to_h16(v.y) << 26);
        }
        {
            int pos = atomicAdd(&cur[c.z >> 9], 1);
            binrec[pos] = (unsigned long long)r.z | ((unsigned long long)(c.z & 511) << 17)
                        | ((unsigned long long)f_to_h16(v.z) << 26);
        }
        {
            int pos = atomicAdd(&cur[c.w >> 9], 1);
            binrec[pos] = (unsigned long long)r.w | ((unsigned long long)(c.w & 511) << 17)
                        | ((unsigned long long)f_to_h16(v.w) << 26);
        }
    }
    if (blk == 0 && t < rem) {
        int e = 4 * E4 + t;
        int c = col[e];
        int pos = atomicAdd(&cur[c >> 9], 1);
        binrec[pos] = (unsigned long long)row[e] | ((unsigned long long)(c & 511) << 17)
                    | ((unsigned long long)f_to_h16(w[e]) << 26);
    }
}

// ---- 4. per-bucket: packed LDS hist -> dinv + off; rank -> ep; h1 *= dinv ----
__global__ __launch_bounds__(256) void k_bucket(
        const unsigned long long* __restrict__ binrec, const int* __restrict__ bktbase,
        float* __restrict__ dinv, int* __restrict__ off, unsigned* __restrict__ ep,
        unsigned short* __restrict__ h1b,
        int E, int N, int nbkt) {
    __shared__ unsigned cnt[512];
    __shared__ int   loff[512];
    __shared__ float dl[512];
    __shared__ int   ssum[256];
    int b = blockIdx.x, t = threadIdx.x;
    int e0 = bktbase[b];
    int e1 = (b == nbkt - 1) ? E : bktbase[b + 1];
    cnt[t] = 0u; cnt[t + 256] = 0u;
    __syncthreads();
    for (int i = e0 + t; i < e1; i += 256) {
        unsigned long long rec = binrec[i];
        int cl = (int)((rec >> 17) & 511);
        float wv = h16_to_f((unsigned short)(rec >> 26));
        atomicAdd(&cnt[cl], (1u << CNT_SHIFT) + (unsigned)(wv * DEG_SCALE + 0.5f));
    }
    __syncthreads();
    unsigned p0 = cnt[2 * t], p1 = cnt[2 * t + 1];
    int c0 = (int)(p0 >> CNT_SHIFT), c1 = (int)(p1 >> CNT_SHIFT);
    float d0 = rsqrtf((float)(p0 & DEG_MASK) * (1.0f / DEG_SCALE) + 1.0f);
    float d1 = rsqrtf((float)(p1 & DEG_MASK) * (1.0f / DEG_SCALE) + 1.0f);
    dl[2 * t] = d0; dl[2 * t + 1] = d1;
    int ps = c0 + c1;
    ssum[t] = ps;
    __syncthreads();
    for (int o = 1; o < 256; o <<= 1) {
        int v = (t >= o) ? ssum[t - o] : 0;
        __syncthreads();
        ssum[t] += v;
        __syncthreads();
    }
    int excl = ssum[t] - ps;
    loff[2 * t] = excl;
    loff[2 * t + 1] = excl + c0;
    int id0 = (b << 9) + 2 * t, id1 = id0 + 1;
    if (id0 < N) dinv[id0] = d0;
    if (id1 < N) dinv[id1] = d1;
    if (id0 <= N) off[id0] = e0 + excl;
    if (id1 <= N) off[id1] = e0 + excl + c0;
    __syncthreads();
    cnt[t] = 0u; cnt[t + 256] = 0u;
    __syncthreads();
    for (int i = e0 + t; i < e1; i += 256) {
        unsigned long long rec = binrec[i];
        int cl  = (int)((rec >> 17) & 511);
        int src = (int)(rec & 0x1FFFF);
        unsigned hb = (unsigned)((rec >> 26) & 0xFFFF);
        int pos = (int)atomicAdd(&cnt[cl], 1u);
        ep[e0 + loff[cl] + pos] = ((unsigned)src << 15) | (hb & 0x7fffu);
    }
    // rescale this bucket's h1 rows: h1' = dinv * h1 (bf16 in-place), ushort4 chunks
    ushort4* h4 = (ushort4*)h1b;
    for (int q = t; q < 512 * 16; q += 256) {
        int node = (b << 9) + (q >> 4);
        if (node >= N) break;                 // q>>4 monotone per thread
        float d = dl[q >> 4];
        size_t idx = (size_t)node * 16 + (q & 15);
        ushort4 hv = h4[idx];
        hv.x = f_to_bf16(bf16_to_f(hv.x) * d);
        hv.y = f_to_bf16(bf16_to_f(hv.y) * d);
        hv.z = f_to_bf16(bf16_to_f(hv.z) * d);
        hv.w = f_to_bf16(bf16_to_f(hv.w) * d);
        h4[idx] = hv;
    }
}

// ---- 5. agg1: acc = sum w*h1'[s] + h1'[i]; h2 = di*( relu(di*acc+b1)@W2 ) ----
__global__ void k_agg1(const unsigned short* __restrict__ h1b, const int* __restrict__ off,
                       const unsigned* __restrict__ ep, const float* __restrict__ dinv,
                       const float* __restrict__ b1, const float* __restrict__ W2,
                       float* __restrict__ h2, int n) {
    int lane = threadIdx.x & 63;
    int wave = threadIdx.x >> 6;
    int i = blockIdx.x * 4 + wave;
    if (i >= n) return;
    float di = dinv[i];
    float acc = bf16_to_f(h1b[(size_t)i * 64 + lane]);   // self (h1' already has dinv)
    int s0 = off[i], s1 = off[i + 1];
    int s = s0;
    for (; s + 4 <= s1; s += 4) {
        unsigned e0 = ep[s], e1 = ep[s + 1], e2 = ep[s + 2], e3 = ep[s + 3];
        float v0 = bf16_to_f(h1b[(size_t)(e0 >> 15) * 64 + lane]);
        float v1 = bf16_to_f(h1b[(size_t)(e1 >> 15) * 64 + lane]);
        float v2 = bf16_to_f(h1b[(size_t)(e2 >> 15) * 64 + lane]);
        float v3 = bf16_to_f(h1b[(size_t)(e3 >> 15) * 64 + lane]);
        acc = fmaf(v0, h16_to_f((unsigned short)(e0 & 0x7fff)), acc);
        acc = fmaf(v1, h16_to_f((unsigned short)(e1 & 0x7fff)), acc);
        acc = fmaf(v2, h16_to_f((unsigned short)(e2 & 0x7fff)), acc);
        acc = fmaf(v3, h16_to_f((unsigned short)(e3 & 0x7fff)), acc);
    }
    for (; s < s1; ++s) {
        unsigned e = ep[s];
        acc = fmaf(bf16_to_f(h1b[(size_t)(e >> 15) * 64 + lane]),
                   h16_to_f((unsigned short)(e & 0x7fff)), acc);
    }
    float v = fmaxf(di * acc + b1[lane], 0.f);
    float p = v * W2[lane];
#pragma unroll
    for (int o = 32; o > 0; o >>= 1) p += __shfl_down(p, o, 64);
    if (lane == 0) h2[i] = di * p;      // t' = dinv * t
}

// ---- 6. agg2: out = dinv*( sum w*t'[s] + t'[i] ) + b2 ----
__global__ void k_agg2(const float* __restrict__ h2, const int* __restrict__ off,
                       const unsigned* __restrict__ ep, const float* __restrict__ dinv,
                       const float* __restrict__ b2, float* __restrict__ out, int n) {
    int i = blockIdx.x * 256 + threadIdx.x;
    if (i >= n) return;
    float acc = h2[i];
    int s0 = off[i], s1 = off[i + 1];
    int s = s0;
    for (; s + 4 <= s1; s += 4) {
        unsigned e0 = ep[s], e1 = ep[s + 1], e2 = ep[s + 2], e3 = ep[s + 3];
        float v0 = h2[e0 >> 15];
        float v1 = h2[e1 >> 15];
        float v2 = h2[e2 >> 15];
        float v3 = h2[e3 >> 15];
        acc = fmaf(v0, h16_to_f((unsigned short)(e0 & 0x7fff)), acc);
        acc = fmaf(v1, h16_to_f((unsigned short)(e1 & 0x7fff)), acc);
        acc = fmaf(v2, h16_to_f((unsigned short)(e2 & 0x7fff)), acc);
        acc = fmaf(v3, h16_to_f((unsigned short)(e3 & 0x7fff)), acc);
    }
    for (; s < s1; ++s) {
        unsigned e = ep[s];
        acc = fmaf(h2[e >> 15], h16_to_f((unsigned short)(e & 0x7fff)), acc);
    }
    out[i] = dinv[i] * acc + b2[0];
}

extern "C" void kernel_launch(void* const* d_in, const int* in_sizes, int n_in,
                              void* d_out, int out_size, void* d_ws, size_t ws_size,
                              hipStream_t stream) {
    const float* x  = (const float*)d_in[0];
    const int*   ei = (const int*)d_in[1];
    const float* w  = (const float*)d_in[2];
    const float* W1 = (const float*)d_in[3];
    const float* b1 = (const float*)d_in[4];
    const float* W2 = (const float*)d_in[5];
    const float* b2 = (const float*)d_in[6];
    float* out = (float*)d_out;

    const int N = in_sizes[0] / 64;
    const int E = in_sizes[2];
    const int* row = ei;
    const int* col = ei + E;

    const int nbkt  = (N + 511) >> 9;
    const int E4    = E / 4;
    const int rem   = E - 4 * E4;
    const int nBlkE = (E4 + 255) / 256;
    const int nGemm = 1024;

    // workspace carve-up (~30 MB); 16B-aligned regions
    char* p = (char*)d_ws;
    auto take = [&](size_t bytes) { char* q = p; p += (bytes + 15) & ~(size_t)15; return q; };
    unsigned long long* binrec = (unsigned long long*)take((size_t)E * 8);
    int* colbase = (int*)take((size_t)nbkt * nBlkE * 4);
    int* tot     = (int*)take((size_t)nbkt * 4);
    int* bktbase = (int*)take((size_t)(nbkt + 1) * 4);
    unsigned* done = (unsigned*)take(16);
    unsigned short* h1b = (unsigned short*)take((size_t)N * 64 * 2);
    float* dinv = (float*)take((size_t)N * 4);
    int*   off  = (int*)take((size_t)(N + 1) * 4);
    unsigned* ep = (unsigned*)take((size_t)E * 4);
    float* h2   = (float*)take((size_t)N * 4);

    k_hist_gemm<<<nBlkE + nGemm, 256, 0, stream>>>((const int4*)col, col, colbase, done,
                                                   x, W1, h1b, E4, rem, nBlkE, nGemm, N, nbkt);
    k_colscan<<<nbkt, 256, 0, stream>>>(colbase, tot, bktbase, done, nBlkE, nbkt);
    k_scatter<<<nBlkE, 256, 0, stream>>>((const int4*)row, (const int4*)col, (const float4*)w,
                                         row, col, w, colbase, bktbase, binrec,
                                         E4, rem, nBlkE, nbkt);
    k_bucket<<<nbkt, 256, 0, stream>>>(binrec, bktbase, dinv, off, ep, h1b, E, N, nbkt);
    k_agg1<<<(N + 3) / 4, 256, 0, stream>>>(h1b, off, ep, dinv, b1, W2, h2, N);
    k_agg2<<<(N + 255) / 256, 256, 0, stream>>>(h2, off, ep, dinv, b2, out, N);
}

// Round 10
// 215.223 us; speedup vs baseline: 1.4574x; 1.0514x over previous
//
#include <hip/hip_runtime.h>
#include <hip/hip_fp16.h>

#define CNT_SHIFT 26
#define DEG_MASK  ((1u << CNT_SHIFT) - 1)
#define DEG_SCALE 1048576.0f   // 2^20

// ---- helpers ----
__device__ __forceinline__ float bf16_to_f(unsigned short u) {
    return __uint_as_float(((unsigned int)u) << 16);
}
__device__ __forceinline__ unsigned short f_to_bf16(float f) {
    unsigned int u = __float_as_uint(f);
    u += 0x7fffu + ((u >> 16) & 1u);
    return (unsigned short)(u >> 16);
}
__device__ __forceinline__ unsigned short f_to_h16(float f) {
    return __half_as_ushort(__float2half(f));
}
__device__ __forceinline__ float h16_to_f(unsigned short u) {
    return __half2float(__ushort_as_half(u));
}
// binrec u64: [16:0]=src row, [25:17]=col&511, [41:26]=f16(w)
// ep u32:     [31:15]=src row, [14:0]=f16(w) sans sign (w>=0)

// ---- 1. pure per-block bucket histogram of col ----
__global__ __launch_bounds__(256) void k_hist(
        const int4* __restrict__ col4, const int* __restrict__ col,
        int* __restrict__ colbase, unsigned* __restrict__ done,
        int E4, int rem, int nBlkE, int nbkt) {
    __shared__ int h[256];
    int blk = blockIdx.x, t = threadIdx.x;
    if (t < nbkt) h[t] = 0;
    if (blk == 0 && t == 0) *done = 0u;
    __syncthreads();
    int g = blk * 256 + t;
    if (g < E4) {
        int4 c = col4[g];
        atomicAdd(&h[c.x >> 9], 1);
        atomicAdd(&h[c.y >> 9], 1);
        atomicAdd(&h[c.z >> 9], 1);
        atomicAdd(&h[c.w >> 9], 1);
    }
    if (blk == 0 && t < rem) atomicAdd(&h[col[4 * E4 + t] >> 9], 1);
    __syncthreads();
    if (t < nbkt) colbase[(size_t)t * nBlkE + blk] = h[t];   // transposed [bkt][blk]
}

// ---- 2. per-bucket scan over blocks (fused bucket-base scan via last-block) ----
__global__ __launch_bounds__(256) void k_colscan(int* __restrict__ colbase,
                                                 int* __restrict__ tot, int* __restrict__ bktbase,
                                                 unsigned* __restrict__ done,
                                                 int nBlkE, int nbkt) {
    __shared__ int ssum[256];
    __shared__ int lastflag;
    int b = blockIdx.x, t = threadIdx.x;
    const int chunk = (nBlkE + 255) >> 8;
    int vals[8];
    int s = 0;
    size_t base = (size_t)b * nBlkE;
#pragma unroll
    for (int k = 0; k < 8; ++k) {
        if (k >= chunk) break;
        int idx = t * chunk + k;
        int v = (idx < nBlkE) ? colbase[base + idx] : 0;
        vals[k] = s; s += v;
    }
    ssum[t] = s;
    __syncthreads();
    for (int o = 1; o < 256; o <<= 1) {
        int v = (t >= o) ? ssum[t - o] : 0;
        __syncthreads();
        ssum[t] += v;
        __syncthreads();
    }
    int texcl = ssum[t] - s;
#pragma unroll
    for (int k = 0; k < 8; ++k) {
        if (k >= chunk) break;
        int idx = t * chunk + k;
        if (idx < nBlkE) colbase[base + idx] = vals[k] + texcl;
    }
    if (t == 255) tot[b] = ssum[255];
    __syncthreads();
    if (t == 0) {
        __threadfence();
        lastflag = (atomicAdd(done, 1u) == (unsigned)(gridDim.x - 1));
    }
    __syncthreads();
    if (lastflag) {
        __threadfence();
        int v = (t < nbkt) ? tot[t] : 0;
        ssum[t] = v;
        __syncthreads();
        for (int o = 1; o < 256; o <<= 1) {
            int u = (t >= o) ? ssum[t - o] : 0;
            __syncthreads();
            ssum[t] += u;
            __syncthreads();
        }
        if (t < nbkt) bktbase[t] = ssum[t] - v;
    }
}

// ---- 3. fused: [0,nBlkE) = bin edges by bucket; rest = h1 = x@W1 ----
__global__ __launch_bounds__(256) void k_scatter_gemm(
        const int4* __restrict__ row4, const int4* __restrict__ col4, const float4* __restrict__ w4,
        const int* __restrict__ row, const int* __restrict__ col, const float* __restrict__ w,
        const int* __restrict__ colbase, const int* __restrict__ bktbase,
        unsigned long long* __restrict__ binrec,
        const float* __restrict__ x, const float* __restrict__ W1,
        unsigned short* __restrict__ h1b,
        int E4, int rem, int nBlkE, int nGemm, int n, int nbkt) {
    __shared__ int cur[256];
    __shared__ float xs[4][512];
    int blk = blockIdx.x, t = threadIdx.x;
    if (blk < nBlkE) {
        if (t < nbkt) cur[t] = bktbase[t] + colbase[(size_t)t * nBlkE + blk];
        __syncthreads();
        int g = blk * 256 + t;
        if (g < E4) {
            int4   r = row4[g];
            int4   c = col4[g];
            float4 v = w4[g];
            {
                int pos = atomicAdd(&cur[c.x >> 9], 1);
                binrec[pos] = (unsigned long long)r.x | ((unsigned long long)(c.x & 511) << 17)
                            | ((unsigned long long)f_to_h16(v.x) << 26);
            }
            {
                int pos = atomicAdd(&cur[c.y >> 9], 1);
                binrec[pos] = (unsigned long long)r.y | ((unsigned long long)(c.y & 511) << 17)
                            | ((unsigned long long)f_to_h16(v.y) << 26);
            }
            {
                int pos = atomicAdd(&cur[c.z >> 9], 1);
                binrec[pos] = (unsigned long long)r.z | ((unsigned long long)(c.z & 511) << 17)
                            | ((unsigned long long)f_to_h16(v.z) << 26);
            }
            {
                int pos = atomicAdd(&cur[c.w >> 9], 1);
                binrec[pos] = (unsigned long long)r.w | ((unsigned long long)(c.w & 511) << 17)
                            | ((unsigned long long)f_to_h16(v.w) << 26);
            }
        }
        if (blk == 0 && t < rem) {
            int e = 4 * E4 + t;
            int c = col[e];
            int pos = atomicAdd(&cur[c >> 9], 1);
            binrec[pos] = (unsigned long long)row[e] | ((unsigned long long)(c & 511) << 17)
                        | ((unsigned long long)f_to_h16(w[e]) << 26);
        }
    } else {
        int b = blk - nBlkE;
        int lane = t & 63, wave = t >> 6;
        float wr[64];                 // W1 column `lane` in registers
#pragma unroll
        for (int k = 0; k < 64; ++k) wr[k] = W1[k * 64 + lane];
        const int stride = nGemm * 32;
        for (int base = b * 32 + wave * 8; base < n; base += stride) {
            if (base + 8 <= n) {
                const float4* xsrc = (const float4*)(x + (size_t)base * 64);
                *(float4*)&xs[wave][4 * lane]       = xsrc[lane];
                *(float4*)&xs[wave][256 + 4 * lane] = xsrc[lane + 64];
            } else {
                const float* xf = x + (size_t)base * 64;
                int valid = (n - base) * 64;
                float4 a0, a1;
                int f0 = 4 * lane, f1 = 256 + 4 * lane;
                a0.x = (f0 + 0 < valid) ? xf[f0 + 0] : 0.f;
                a0.y = (f0 + 1 < valid) ? xf[f0 + 1] : 0.f;
                a0.z = (f0 + 2 < valid) ? xf[f0 + 2] : 0.f;
                a0.w = (f0 + 3 < valid) ? xf[f0 + 3] : 0.f;
                a1.x = (f1 + 0 < valid) ? xf[f1 + 0] : 0.f;
                a1.y = (f1 + 1 < valid) ? xf[f1 + 1] : 0.f;
                a1.z = (f1 + 2 < valid) ? xf[f1 + 2] : 0.f;
                a1.w = (f1 + 3 < valid) ? xf[f1 + 3] : 0.f;
                *(float4*)&xs[wave][4 * lane]       = a0;
                *(float4*)&xs[wave][256 + 4 * lane] = a1;
            }
#pragma unroll
            for (int nn = 0; nn < 8; ++nn) {
                int i = base + nn;
                if (i >= n) break;
                float acc = 0.f;
#pragma unroll
                for (int k4 = 0; k4 < 16; ++k4) {
                    float4 xv = *(const float4*)&xs[wave][nn * 64 + 4 * k4];  // broadcast
                    acc = fmaf(xv.x, wr[4 * k4 + 0], acc);
                    acc = fmaf(xv.y, wr[4 * k4 + 1], acc);
                    acc = fmaf(xv.z, wr[4 * k4 + 2], acc);
                    acc = fmaf(xv.w, wr[4 * k4 + 3], acc);
                }
                h1b[(size_t)i * 64 + lane] = f_to_bf16(acc);
            }
        }
    }
}

// ---- 4. per-bucket: packed LDS hist -> dinv + off; rank -> ep; h1 *= dinv ----
__global__ __launch_bounds__(256) void k_bucket(
        const unsigned long long* __restrict__ binrec, const int* __restrict__ bktbase,
        float* __restrict__ dinv, int* __restrict__ off, unsigned* __restrict__ ep,
        unsigned short* __restrict__ h1b,
        int E, int N, int nbkt) {
    __shared__ unsigned cnt[512];
    __shared__ int   loff[512];
    __shared__ float dl[512];
    __shared__ int   ssum[256];
    int b = blockIdx.x, t = threadIdx.x;
    int e0 = bktbase[b];
    int e1 = (b == nbkt - 1) ? E : bktbase[b + 1];
    cnt[t] = 0u; cnt[t + 256] = 0u;
    __syncthreads();
    for (int i = e0 + t; i < e1; i += 256) {
        unsigned long long rec = binrec[i];
        int cl = (int)((rec >> 17) & 511);
        float wv = h16_to_f((unsigned short)(rec >> 26));
        atomicAdd(&cnt[cl], (1u << CNT_SHIFT) + (unsigned)(wv * DEG_SCALE + 0.5f));
    }
    __syncthreads();
    unsigned p0 = cnt[2 * t], p1 = cnt[2 * t + 1];
    int c0 = (int)(p0 >> CNT_SHIFT), c1 = (int)(p1 >> CNT_SHIFT);
    float d0 = rsqrtf((float)(p0 & DEG_MASK) * (1.0f / DEG_SCALE) + 1.0f);
    float d1 = rsqrtf((float)(p1 & DEG_MASK) * (1.0f / DEG_SCALE) + 1.0f);
    dl[2 * t] = d0; dl[2 * t + 1] = d1;
    int ps = c0 + c1;
    ssum[t] = ps;
    __syncthreads();
    for (int o = 1; o < 256; o <<= 1) {
        int v = (t >= o) ? ssum[t - o] : 0;
        __syncthreads();
        ssum[t] += v;
        __syncthreads();
    }
    int excl = ssum[t] - ps;
    loff[2 * t] = excl;
    loff[2 * t + 1] = excl + c0;
    int id0 = (b << 9) + 2 * t, id1 = id0 + 1;
    if (id0 < N) dinv[id0] = d0;
    if (id1 < N) dinv[id1] = d1;
    if (id0 <= N) off[id0] = e0 + excl;
    if (id1 <= N) off[id1] = e0 + excl + c0;
    __syncthreads();
    cnt[t] = 0u; cnt[t + 256] = 0u;
    __syncthreads();
    for (int i = e0 + t; i < e1; i += 256) {
        unsigned long long rec = binrec[i];
        int cl  = (int)((rec >> 17) & 511);
        int src = (int)(rec & 0x1FFFF);
        unsigned hb = (unsigned)((rec >> 26) & 0xFFFF);
        int pos = (int)atomicAdd(&cnt[cl], 1u);
        ep[e0 + loff[cl] + pos] = ((unsigned)src << 15) | (hb & 0x7fffu);
    }
    // rescale this bucket's h1 rows: h1' = dinv * h1 (bf16 in-place)
    ushort4* h4 = (ushort4*)h1b;
    for (int q = t; q < 512 * 16; q += 256) {
        int node = (b << 9) + (q >> 4);
        if (node >= N) break;
        float d = dl[q >> 4];
        size_t idx = (size_t)node * 16 + (q & 15);
        ushort4 hv = h4[idx];
        hv.x = f_to_bf16(bf16_to_f(hv.x) * d);
        hv.y = f_to_bf16(bf16_to_f(hv.y) * d);
        hv.z = f_to_bf16(bf16_to_f(hv.z) * d);
        hv.w = f_to_bf16(bf16_to_f(hv.w) * d);
        h4[idx] = hv;
    }
}

// ---- 5. agg1: acc = sum w*h1'[s] + h1'[i]; h2 = di*( relu(di*acc+b1)@W2 ) ----
__global__ void k_agg1(const unsigned short* __restrict__ h1b, const int* __restrict__ off,
                       const unsigned* __restrict__ ep, const float* __restrict__ dinv,
                       const float* __restrict__ b1, const float* __restrict__ W2,
                       float* __restrict__ h2, int n) {
    int lane = threadIdx.x & 63;
    int wave = threadIdx.x >> 6;
    int i = blockIdx.x * 4 + wave;
    if (i >= n) return;
    float di = dinv[i];
    float acc = bf16_to_f(h1b[(size_t)i * 64 + lane]);   // self (h1' already has dinv)
    int s0 = off[i], s1 = off[i + 1];
    int s = s0;
    for (; s + 8 <= s1; s += 8) {       // 8 gathers in flight
        unsigned e0 = ep[s],     e1 = ep[s + 1], e2 = ep[s + 2], e3 = ep[s + 3];
        unsigned e4 = ep[s + 4], e5 = ep[s + 5], e6 = ep[s + 6], e7 = ep[s + 7];
        float v0 = bf16_to_f(h1b[(size_t)(e0 >> 15) * 64 + lane]);
        float v1 = bf16_to_f(h1b[(size_t)(e1 >> 15) * 64 + lane]);
        float v2 = bf16_to_f(h1b[(size_t)(e2 >> 15) * 64 + lane]);
        float v3 = bf16_to_f(h1b[(size_t)(e3 >> 15) * 64 + lane]);
        float v4 = bf16_to_f(h1b[(size_t)(e4 >> 15) * 64 + lane]);
        float v5 = bf16_to_f(h1b[(size_t)(e5 >> 15) * 64 + lane]);
        float v6 = bf16_to_f(h1b[(size_t)(e6 >> 15) * 64 + lane]);
        float v7 = bf16_to_f(h1b[(size_t)(e7 >> 15) * 64 + lane]);
        acc = fmaf(v0, h16_to_f((unsigned short)(e0 & 0x7fff)), acc);
        acc = fmaf(v1, h16_to_f((unsigned short)(e1 & 0x7fff)), acc);
        acc = fmaf(v2, h16_to_f((unsigned short)(e2 & 0x7fff)), acc);
        acc = fmaf(v3, h16_to_f((unsigned short)(e3 & 0x7fff)), acc);
        acc = fmaf(v4, h16_to_f((unsigned short)(e4 & 0x7fff)), acc);
        acc = fmaf(v5, h16_to_f((unsigned short)(e5 & 0x7fff)), acc);
        acc = fmaf(v6, h16_to_f((unsigned short)(e6 & 0x7fff)), acc);
        acc = fmaf(v7, h16_to_f((unsigned short)(e7 & 0x7fff)), acc);
    }
    for (; s + 4 <= s1; s += 4) {
        unsigned e0 = ep[s], e1 = ep[s + 1], e2 = ep[s + 2], e3 = ep[s + 3];
        float v0 = bf16_to_f(h1b[(size_t)(e0 >> 15) * 64 + lane]);
        float v1 = bf16_to_f(h1b[(size_t)(e1 >> 15) * 64 + lane]);
        float v2 = bf16_to_f(h1b[(size_t)(e2 >> 15) * 64 + lane]);
        float v3 = bf16_to_f(h1b[(size_t)(e3 >> 15) * 64 + lane]);
        acc = fmaf(v0, h16_to_f((unsigned short)(e0 & 0x7fff)), acc);
        acc = fmaf(v1, h16_to_f((unsigned short)(e1 & 0x7fff)), acc);
        acc = fmaf(v2, h16_to_f((unsigned short)(e2 & 0x7fff)), acc);
        acc = fmaf(v3, h16_to_f((unsigned short)(e3 & 0x7fff)), acc);
    }
    for (; s < s1; ++s) {
        unsigned e = ep[s];
        acc = fmaf(bf16_to_f(h1b[(size_t)(e >> 15) * 64 + lane]),
                   h16_to_f((unsigned short)(e & 0x7fff)), acc);
    }
    float v = fmaxf(di * acc + b1[lane], 0.f);
    float p = v * W2[lane];
#pragma unroll
    for (int o = 32; o > 0; o >>= 1) p += __shfl_down(p, o, 64);
    if (lane == 0) h2[i] = di * p;      // t' = dinv * t
}

// ---- 6. agg2: out = dinv*( sum w*t'[s] + t'[i] ) + b2 ----
__global__ void k_agg2(const float* __restrict__ h2, const int* __restrict__ off,
                       const unsigned* __restrict__ ep, const float* __restrict__ dinv,
                       const float* __restrict__ b2, float* __restrict__ out, int n) {
    int i = blockIdx.x * 256 + threadIdx.x;
    if (i >= n) return;
    float acc = h2[i];
    int s0 = off[i], s1 = off[i + 1];
    int s = s0;
    for (; s + 8 <= s1; s += 8) {
        unsigned e0 = ep[s],     e1 = ep[s + 1], e2 = ep[s + 2], e3 = ep[s + 3];
        unsigned e4 = ep[s + 4], e5 = ep[s + 5], e6 = ep[s + 6], e7 = ep[s + 7];
        float v0 = h2[e0 >> 15], v1 = h2[e1 >> 15], v2 = h2[e2 >> 15], v3 = h2[e3 >> 15];
        float v4 = h2[e4 >> 15], v5 = h2[e5 >> 15], v6 = h2[e6 >> 15], v7 = h2[e7 >> 15];
        acc = fmaf(v0, h16_to_f((unsigned short)(e0 & 0x7fff)), acc);
        acc = fmaf(v1, h16_to_f((unsigned short)(e1 & 0x7fff)), acc);
        acc = fmaf(v2, h16_to_f((unsigned short)(e2 & 0x7fff)), acc);
        acc = fmaf(v3, h16_to_f((unsigned short)(e3 & 0x7fff)), acc);
        acc = fmaf(v4, h16_to_f((unsigned short)(e4 & 0x7fff)), acc);
        acc = fmaf(v5, h16_to_f((unsigned short)(e5 & 0x7fff)), acc);
        acc = fmaf(v6, h16_to_f((unsigned short)(e6 & 0x7fff)), acc);
        acc = fmaf(v7, h16_to_f((unsigned short)(e7 & 0x7fff)), acc);
    }
    for (; s + 4 <= s1; s += 4) {
        unsigned e0 = ep[s], e1 = ep[s + 1], e2 = ep[s + 2], e3 = ep[s + 3];
        float v0 = h2[e0 >> 15], v1 = h2[e1 >> 15], v2 = h2[e2 >> 15], v3 = h2[e3 >> 15];
        acc = fmaf(v0, h16_to_f((unsigned short)(e0 & 0x7fff)), acc);
        acc = fmaf(v1, h16_to_f((unsigned short)(e1 & 0x7fff)), acc);
        acc = fmaf(v2, h16_to_f((unsigned short)(e2 & 0x7fff)), acc);
        acc = fmaf(v3, h16_to_f((unsigned short)(e3 & 0x7fff)), acc);
    }
    for (; s < s1; ++s) {
        unsigned e = ep[s];
        acc = fmaf(h2[e >> 15], h16_to_f((unsigned short)(e & 0x7fff)), acc);
    }
    out[i] = dinv[i] * acc + b2[0];
}

extern "C" void kernel_launch(void* const* d_in, const int* in_sizes, int n_in,
                              void* d_out, int out_size, void* d_ws, size_t ws_size,
                              hipStream_t stream) {
    const float* x  = (const float*)d_in[0];
    const int*   ei = (const int*)d_in[1];
    const float* w  = (const float*)d_in[2];
    const float* W1 = (const float*)d_in[3];
    const float* b1 = (const float*)d_in[4];
    const float* W2 = (const float*)d_in[5];
    const float* b2 = (const float*)d_in[6];
    float* out = (float*)d_out;

    const int N = in_sizes[0] / 64;
    const int E = in_sizes[2];
    const int* row = ei;
    const int* col = ei + E;

    const int nbkt  = (N + 511) >> 9;
    const int E4    = E / 4;
    const int rem   = E - 4 * E4;
    const int nBlkE = (E4 + 255) / 256;
    const int nGemm = 1024;

    // workspace carve-up (~30 MB); 16B-aligned regions
    char* p = (char*)d_ws;
    auto take = [&](size_t bytes) { char* q = p; p += (bytes + 15) & ~(size_t)15; return q; };
    unsigned long long* binrec = (unsigned long long*)take((size_t)E * 8);
    int* colbase = (int*)take((size_t)nbkt * nBlkE * 4);
    int* tot     = (int*)take((size_t)nbkt * 4);
    int* bktbase = (int*)take((size_t)(nbkt + 1) * 4);
    unsigned* done = (unsigned*)take(16);
    unsigned short* h1b = (unsigned short*)take((size_t)N * 64 * 2);
    float* dinv = (float*)take((size_t)N * 4);
    int*   off  = (int*)take((size_t)(N + 1) * 4);
    unsigned* ep = (unsigned*)take((size_t)E * 4);
    float* h2   = (float*)take((size_t)N * 4);

    k_hist<<<nBlkE, 256, 0, stream>>>((const int4*)col, col, colbase, done,
                                      E4, rem, nBlkE, nbkt);
    k_colscan<<<nbkt, 256, 0, stream>>>(colbase, tot, bktbase, done, nBlkE, nbkt);
    k_scatter_gemm<<<nBlkE + nGemm, 256, 0, stream>>>(
        (const int4*)row, (const int4*)col, (const float4*)w,
        row, col, w, colbase, bktbase, binrec, x, W1, h1b,
        E4, rem, nBlkE, nGemm, N, nbkt);
    k_bucket<<<nbkt, 256, 0, stream>>>(binrec, bktbase, dinv, off, ep, h1b, E, N, nbkt);
    k_agg1<<<(N + 3) / 4, 256, 0, stream>>>(h1b, off, ep, dinv, b1, W2, h2, N);
    k_agg2<<<(N + 255) / 256, 256, 0, stream>>>(h2, off, ep, dinv, b2, out, N);
}